// Round 18
// baseline (265.074 us; speedup 1.0000x reference)
//
#include <hip/hip_runtime.h>
#include <hip/hip_bf16.h>
#include <math.h>

// Problem constants (from reference)
#define BATCH   64
#define NNODES  256
#define HID     256
#define HEADS   4
#define CDIM    64
#define NEDGES  8192
#define NEG_SLOPE 0.2f
#define EPS_BN 1e-5f

// All intermediate activations use NODE-MAJOR layout: row = node*64 + batch.
// Lin weights pre-packed into K-tile panels: [K/32][256 n][32 k] bf16.

typedef __bf16 bf16_t;
typedef __bf16 bf16x8 __attribute__((ext_vector_type(8)));
typedef float  f32x4  __attribute__((ext_vector_type(4)));
typedef float  f32x2  __attribute__((ext_vector_type(2)));
typedef unsigned int u32;
typedef u32 u32x4v __attribute__((ext_vector_type(4)));

__device__ __forceinline__ float gelu_f(float x) {
    return 0.5f * x * (1.0f + erff(x * 0.70710678118654752440f));
}

__device__ __forceinline__ f32x2 vmax2(f32x2 a, f32x2 b) {
#if __has_builtin(__builtin_elementwise_max)
    return __builtin_elementwise_max(a, b);
#else
    f32x2 r; r[0] = fmaxf(a[0], b[0]); r[1] = fmaxf(a[1], b[1]); return r;
#endif
}

// bf16 pair (packed in u32) -> 2 floats: 1 VALU per element.
__device__ __forceinline__ f32x2 unpk(u32 u) {
    f32x2 f;
    f[0] = __builtin_bit_cast(float, u << 16);
    f[1] = __builtin_bit_cast(float, u & 0xffff0000u);
    return f;
}

// LDS bank swizzle for 16B chunks.
#define SWZ(r, c) ((c) ^ ((r) & 3) ^ (((r) >> 2) & 3) ^ (((r) >> 4) & 3))

// ---------------------------------------------------------------------------
// HEAD kernel (R16/R17 structure — measured best, ~bandwidth-floor-bound
// against the concurrent harness fill): CSR at block 0, packs 1..256,
// node_proj 257..768, single-barrier dbuf K-loop.
// ---------------------------------------------------------------------------
__global__ __launch_bounds__(256, 4) void head_kernel(
        const float* __restrict__ x, const float* __restrict__ W1,
        const float* __restrict__ b1, const float* __restrict__ g1,
        const float* __restrict__ be1, const float* __restrict__ m1,
        const float* __restrict__ v1, bf16_t* __restrict__ H,
        const int* __restrict__ ei,
        const float* __restrict__ Wa, const float* __restrict__ Wb,
        const float* __restrict__ Wc, const float* __restrict__ Wd,
        int* __restrict__ noff, int* __restrict__ csrc,
        bf16_t* __restrict__ Ta, bf16_t* __restrict__ Tb,
        bf16_t* __restrict__ Tc, bf16_t* __restrict__ Td) {
    __shared__ char smem[36 * 1024];
    const int bx  = blockIdx.x;
    const int tid = threadIdx.x;

    if (bx == 0) {
        // ---- CSR build ----
        int* cnt = (int*)smem;
        int* sc  = cnt + NNODES;
        cnt[tid] = 0;
        __syncthreads();
        for (int e = tid; e < NEDGES; e += 256) atomicAdd(&cnt[ei[NEDGES + e]], 1);
        __syncthreads();
        sc[tid] = cnt[tid];
        __syncthreads();
        #pragma unroll
        for (int ofs = 1; ofs < 256; ofs <<= 1) {
            const int t = (tid >= ofs) ? sc[tid - ofs] : 0;
            __syncthreads();
            sc[tid] += t;
            __syncthreads();
        }
        const int excl = sc[tid] - cnt[tid];
        noff[tid] = excl;
        if (tid == 255) noff[NNODES] = sc[255];
        cnt[tid] = excl;
        __syncthreads();
        for (int e = tid; e < NEDGES; e += 256) {
            int d = ei[NEDGES + e];
            int p = atomicAdd(&cnt[d], 1);
            csrc[p] = ei[e];
        }
        return;
    }
    if (bx <= 256) {
        // ---- lin-weight panel pack ----
        float (*tile)[33] = (float(*)[33])smem;
        const int idx = bx - 1, mid = idx >> 6, t = idx & 63;
        const float* in; bf16_t* out;
        if (mid == 0) { in = Wa; out = Ta; }
        else if (mid == 1) { in = Wb; out = Tb; }
        else if (mid == 2) { in = Wc; out = Tc; }
        else { in = Wd; out = Td; }
        const int kt = t >> 3, nt = t & 7;
        const int k0 = kt * 32, n0 = nt * 32;
        const int xx = tid & 31, y = tid >> 5;
        #pragma unroll
        for (int j = 0; j < 4; ++j)
            tile[y + j * 8][xx] = in[(size_t)(k0 + y + j * 8) * 256 + n0 + xx];
        __syncthreads();
        #pragma unroll
        for (int j = 0; j < 4; ++j) {
            const int n = n0 + y + j * 8;
            out[((size_t)kt * 256 + n) * 32 + xx] = (bf16_t)tile[xx][y + j * 8];
        }
        return;
    }

    // ---- node_proj GEMM: H = gelu(BN(x @ W1 + b1)), bf16 node-major out ----
    bf16_t (*As)[32 * 32]  = (bf16_t(*)[32 * 32])smem;
    bf16_t (*Bs)[256 * 32] = (bf16_t(*)[256 * 32])(smem + 4096);
    const int K = 768;
    const int lane = tid & 63;
    const int wv   = tid >> 6;
    const int mblk = (bx - 257) * 32;

    f32x4 acc[2][4];
    #pragma unroll
    for (int f = 0; f < 2; ++f)
        #pragma unroll
        for (int t = 0; t < 4; ++t) acc[f][t] = (f32x4){0.f, 0.f, 0.f, 0.f};

    const int arow = (tid & 127) >> 2;
    const int achk = tid & 3;
    const int gr   = mblk + arow;
    const int arr  = (gr & 63) * 256 + (gr >> 6);    // batch-major source row
    const int fm   = lane & 15, q = lane >> 4;
    const int nq   = tid & 63;
    const int kg   = tid >> 6;

    f32x4 a0, a1;
    f32x4 bw[8];
    if (tid < 128) {
        const float* ap = x + (size_t)arr * K + achk * 8;
        a0 = *(const f32x4*)ap; a1 = *(const f32x4*)(ap + 4);
    }
    {
        const float* wp = W1 + (size_t)(kg * 8) * 256 + nq * 4;
        #pragma unroll
        for (int j = 0; j < 8; ++j) bw[j] = *(const f32x4*)(wp + j * 256);
    }

    #pragma unroll
    for (int kt = 0; kt < 24; ++kt) {
        const int buf = kt & 1;
        if (tid < 128) {
            bf16x8 v;
            #pragma unroll
            for (int j = 0; j < 4; ++j) { v[j] = (bf16_t)a0[j]; v[4 + j] = (bf16_t)a1[j]; }
            *(bf16x8*)(&As[buf][(arow * 4 + SWZ(arow, achk)) * 8]) = v;
        }
        #pragma unroll
        for (int i = 0; i < 4; ++i) {
            const int n = nq * 4 + i;
            bf16x8 v;
            #pragma unroll
            for (int j = 0; j < 8; ++j) v[j] = (bf16_t)bw[j][i];
            *(bf16x8*)(&Bs[buf][(n * 4 + SWZ(n, kg)) * 8]) = v;
        }
        __syncthreads();
        if (kt + 1 < 24) {
            const int k0 = (kt + 1) * 32;
            if (tid < 128) {
                const float* ap = x + (size_t)arr * K + k0 + achk * 8;
                a0 = *(const f32x4*)ap; a1 = *(const f32x4*)(ap + 4);
            }
            const float* wp = W1 + (size_t)(k0 + kg * 8) * 256 + nq * 4;
            #pragma unroll
            for (int j = 0; j < 8; ++j) bw[j] = *(const f32x4*)(wp + j * 256);
        }
        bf16x8 af[2], bfv[4];
        #pragma unroll
        for (int f = 0; f < 2; ++f) {
            const int r = f * 16 + fm;
            af[f] = *(const bf16x8*)(&As[buf][(r * 4 + SWZ(r, q)) * 8]);
        }
        #pragma unroll
        for (int t = 0; t < 4; ++t) {
            const int n = wv * 64 + t * 16 + fm;
            bfv[t] = *(const bf16x8*)(&Bs[buf][(n * 4 + SWZ(n, q)) * 8]);
        }
        #pragma unroll
        for (int f = 0; f < 2; ++f)
            #pragma unroll
            for (int t = 0; t < 4; ++t)
                acc[f][t] = __builtin_amdgcn_mfma_f32_16x16x32_bf16(
                    af[f], bfv[t], acc[f][t], 0, 0, 0);
    }

    const int quad = lane >> 4, cn = lane & 15;
    #pragma unroll
    for (int t = 0; t < 4; ++t) {
        const int n = wv * 64 + t * 16 + cn;
        const float s = g1[n] * rsqrtf(v1[n] + EPS_BN);
        const float shift = (b1[n] - m1[n]) * s + be1[n];
        #pragma unroll
        for (int f = 0; f < 2; ++f) {
            #pragma unroll
            for (int r = 0; r < 4; ++r) {
                const int m = mblk + f * 16 + quad * 4 + r;
                H[(size_t)m * 256 + n] = (bf16_t)gelu_f(acc[f][t][r] * s + shift);
            }
        }
    }
}

// ---------------------------------------------------------------------------
// MFMA bf16 dual GEMM (R15/R17 verbatim — measured best): tile 32(M) x 256(N),
// BK=32, single-barrier pipelined dbuf, 1024 blocks (4/CU).
// ---------------------------------------------------------------------------
template<int KTILES>
__global__ __launch_bounds__(256, 4) void gemm_kernel(
        const bf16_t* __restrict__ Ap,
        const bf16_t* __restrict__ Bt0, const bf16_t* __restrict__ Bt1,
        bf16_t* __restrict__ C0p, bf16_t* __restrict__ C1p,
        const float* __restrict__ bias0, const float* __restrict__ bias1) {
    __shared__ bf16_t As[2][32 * 32];
    __shared__ bf16_t Bs[2][256 * 32];
    const int K = KTILES * 32;
    const int tid  = threadIdx.x;
    const int lane = tid & 63;
    const int wv   = tid >> 6;
    const int mblk = blockIdx.y * 32;
    const bool second = (blockIdx.x == 1);
    const bf16_t* Bt = second ? Bt1 : Bt0;
    bf16_t* Cp = second ? C1p : C0p;
    const float* bias = second ? bias1 : bias0;

    f32x4 acc[2][4];
    #pragma unroll
    for (int f = 0; f < 2; ++f)
        #pragma unroll
        for (int t = 0; t < 4; ++t) acc[f][t] = (f32x4){0.f, 0.f, 0.f, 0.f};

    const int arow = (tid & 127) >> 2;
    const int achk = tid & 3;
    const int fm   = lane & 15, q = lane >> 4;
    const int bn   = tid >> 2;

    bf16x8 aReg; bf16x8 bReg[4];
    if (tid < 128)
        aReg = *(const bf16x8*)(Ap + (size_t)(mblk + arow) * K + achk * 8);
    {
        const bf16_t* panel = Bt + (size_t)tid * 8;
        #pragma unroll
        for (int c = 0; c < 4; ++c) bReg[c] = *(const bf16x8*)(panel + c * 2048);
    }

    #pragma unroll
    for (int kt = 0; kt < KTILES; ++kt) {
        const int buf = kt & 1;
        if (tid < 128)
            *(bf16x8*)(&As[buf][(arow * 4 + SWZ(arow, achk)) * 8]) = aReg;
        #pragma unroll
        for (int c = 0; c < 4; ++c) {
            const int n = c * 64 + bn;
            *(bf16x8*)(&Bs[buf][(n * 4 + SWZ(n, achk)) * 8]) = bReg[c];
        }
        __syncthreads();
        if (kt + 1 < KTILES) {
            const int k0 = (kt + 1) * 32;
            if (tid < 128)
                aReg = *(const bf16x8*)(Ap + (size_t)(mblk + arow) * K + k0 + achk * 8);
            const bf16_t* panel = Bt + (size_t)(kt + 1) * (256 * 32) + (size_t)tid * 8;
            #pragma unroll
            for (int c = 0; c < 4; ++c) bReg[c] = *(const bf16x8*)(panel + c * 2048);
        }
        bf16x8 af[2], bfv[4];
        #pragma unroll
        for (int f = 0; f < 2; ++f) {
            const int r = f * 16 + fm;
            af[f] = *(const bf16x8*)(&As[buf][(r * 4 + SWZ(r, q)) * 8]);
        }
        #pragma unroll
        for (int t = 0; t < 4; ++t) {
            const int n = wv * 64 + t * 16 + fm;
            bfv[t] = *(const bf16x8*)(&Bs[buf][(n * 4 + SWZ(n, q)) * 8]);
        }
        #pragma unroll
        for (int f = 0; f < 2; ++f)
            #pragma unroll
            for (int t = 0; t < 4; ++t)
                acc[f][t] = __builtin_amdgcn_mfma_f32_16x16x32_bf16(
                    af[f], bfv[t], acc[f][t], 0, 0, 0);
    }

    const int quad = lane >> 4, cn = lane & 15;
    #pragma unroll
    for (int t = 0; t < 4; ++t) {
        const int n = wv * 64 + t * 16 + cn;
        const float bv = bias[n];
        #pragma unroll
        for (int f = 0; f < 2; ++f) {
            #pragma unroll
            for (int r = 0; r < 4; ++r) {
                const int m = mblk + f * 16 + quad * 4 + r;
                Cp[(size_t)m * 256 + n] = (bf16_t)(acc[f][t][r] + bv);
            }
        }
    }
}

// ---------------------------------------------------------------------------
// GATv2 edge softmax + aggregate — 4-chain ILP (prefetch distance 4 edges,
// 2x the latency hiding of R13's 2-chain). Packed math, no online max,
// node-major, XCD-swizzled.
// ---------------------------------------------------------------------------
__global__ __launch_bounds__(256) void edge_kernel(
        const bf16_t* __restrict__ XL, const bf16_t* __restrict__ XR,
        const float* __restrict__ att, const float* __restrict__ bo,
        const int* __restrict__ noff, const int* __restrict__ csrc,
        bf16_t* __restrict__ Hout) {
    const int bid  = blockIdx.x;
    const int i    = bid >> 3;
    const int tid  = threadIdx.x;
    const int w    = tid >> 6;
    const int lane = tid & 63;
    const int bg   = lane >> 3;
    const int cg   = lane & 7;
    const int b    = (bid & 7) * 8 + bg;
    const int cbase = w * CDIM + cg * 8;
    const size_t orow = ((size_t)i * BATCH + b) * HID + cbase;
    const float* bor = bo + cbase;

    const int s0 = noff[i], s1 = noff[i + 1];
    if (s0 == s1) {
        bf16x8 ov;
        #pragma unroll
        for (int q = 0; q < 8; ++q) ov[q] = (bf16_t)gelu_f(bor[q]);
        *(bf16x8*)(Hout + orow) = ov;
        return;
    }

    f32x2 att2[4], xi2[4];
    {
        const u32x4v xr = *(const u32x4v*)(XR + orow);
        #pragma unroll
        for (int k = 0; k < 4; ++k) {
            att2[k] = *(const f32x2*)(att + cbase + 2 * k);
            xi2[k]  = unpk(xr[k]);
        }
    }

    const bf16_t* XLb = XL + (size_t)b * HID + cbase;
    const size_t RSTR = (size_t)BATCH * HID;

    float den[4];
    f32x2 acc[4][4];
    #pragma unroll
    for (int c = 0; c < 4; ++c) {
        den[c] = 0.f;
        #pragma unroll
        for (int k = 0; k < 4; ++k) acc[c][k] = (f32x2){0.f, 0.f};
    }

    u32x4v u[4];
    #pragma unroll
    for (int c = 0; c < 4; ++c) {
        const int e = s0 + c;
        const int j = csrc[(e < s1) ? e : s0];
        u[c] = *(const u32x4v*)(XLb + (size_t)j * RSTR);
    }

    for (int e0 = s0; e0 < s1; e0 += 4) {
        // prefetch next 4 edges (clamped indices keep addresses valid)
        u32x4v un[4];
        #pragma unroll
        for (int c = 0; c < 4; ++c) {
            const int en = e0 + 4 + c;
            const int jn = csrc[(en < s1) ? en : s0];
            un[c] = *(const u32x4v*)(XLb + (size_t)jn * RSTR);
        }

        f32x2 fv[4][4];
        float p[4];
        #pragma unroll
        for (int c = 0; c < 4; ++c) {
            f32x2 p2 = (f32x2){0.f, 0.f};
            #pragma unroll
            for (int k = 0; k < 4; ++k) {
                fv[c][k] = unpk(u[c][k]);
                const f32x2 z = xi2[k] + fv[c][k];
                const f32x2 m = vmax2(z, z * 0.2f);
                p2 += att2[k] * m;
            }
            p[c] = p2[0] + p2[1];
        }
        #pragma unroll
        for (int c = 0; c < 4; ++c) p[c] += __shfl_xor(p[c], 1, 64);
        #pragma unroll
        for (int c = 0; c < 4; ++c) p[c] += __shfl_xor(p[c], 2, 64);
        #pragma unroll
        for (int c = 0; c < 4; ++c) p[c] += __shfl_xor(p[c], 4, 64);

        #pragma unroll
        for (int c = 0; c < 4; ++c) {
            const float valid = ((e0 + c) < s1) ? 1.f : 0.f;
            const float wc = valid * __expf(p[c]);
            den[c] += wc;
            const f32x2 w2 = (f32x2){wc, wc};
            #pragma unroll
            for (int k = 0; k < 4; ++k) acc[c][k] += w2 * fv[c][k];
        }
        #pragma unroll
        for (int c = 0; c < 4; ++c) u[c] = un[c];
    }

    const float inv = 1.0f / (den[0] + den[1] + den[2] + den[3] + 1e-16f);
    bf16x8 ov;
    #pragma unroll
    for (int k = 0; k < 4; ++k) {
        const f32x2 bo2 = *(const f32x2*)(bor + 2 * k);
        const f32x2 o2 = (acc[0][k] + acc[1][k] + acc[2][k] + acc[3][k]) * inv + bo2;
        ov[2 * k]     = (bf16_t)gelu_f(o2[0]);
        ov[2 * k + 1] = (bf16_t)gelu_f(o2[1]);
    }
    *(bf16x8*)(Hout + orow) = ov;
}

// ---------------------------------------------------------------------------
// Mean-pool partials: grid (64 b, 16 c); block sums 16 nodes (short chains).
// ---------------------------------------------------------------------------
__global__ __launch_bounds__(256) void pool_kernel(const bf16_t* __restrict__ H1,
                                                   float* __restrict__ P) {
    const int b = blockIdx.x, c = blockIdx.y, f = threadIdx.x;
    const bf16_t* p = H1 + ((size_t)(c * 16) * BATCH + b) * HID + f;
    float s = 0.f;
    #pragma unroll
    for (int n = 0; n < 16; ++n) s += (float)p[(size_t)n * BATCH * HID];
    P[((size_t)b * 16 + c) * HID + f] = s;
}

// ---------------------------------------------------------------------------
// Output proj: out = gelu(BN(pooled @ W2 + b2)), pooled from 16 partials.
// ---------------------------------------------------------------------------
__global__ __launch_bounds__(256) void final_kernel(
        const float* __restrict__ P, const float* __restrict__ W2,
        const float* __restrict__ b2, const float* __restrict__ g2,
        const float* __restrict__ be2, const float* __restrict__ m2,
        const float* __restrict__ v2, float* __restrict__ out) {
    __shared__ float pl[HID];
    const int b = blockIdx.x, f = threadIdx.x;
    float s4 = 0.f;
    #pragma unroll
    for (int c = 0; c < 16; ++c) s4 += P[((size_t)b * 16 + c) * HID + f];
    pl[f] = s4 * (1.0f / (float)NNODES);
    __syncthreads();
    float s = 0.f;
    for (int k = 0; k < HID; ++k) s += pl[k] * W2[(size_t)k * HID + f];
    s += b2[f];
    const float scale = g2[f] * rsqrtf(v2[f] + EPS_BN);
    s = (s - m2[f]) * scale + be2[f];
    out[b * HID + f] = gelu_f(s);
}

// ---------------------------------------------------------------------------
extern "C" void kernel_launch(void* const* d_in, const int* in_sizes, int n_in,
                              void* d_out, int out_size, void* d_ws, size_t ws_size,
                              hipStream_t stream) {
    const float* x    = (const float*)d_in[0];
    const int*   ei   = (const int*)d_in[1];
    const float* W1   = (const float*)d_in[2];
    const float* b1   = (const float*)d_in[3];
    const float* g1   = (const float*)d_in[4];
    const float* be1  = (const float*)d_in[5];
    const float* m1   = (const float*)d_in[6];
    const float* v1   = (const float*)d_in[7];
    const float* Wl0  = (const float*)d_in[8];
    const float* bl0  = (const float*)d_in[9];
    const float* Wr0  = (const float*)d_in[10];
    const float* br0  = (const float*)d_in[11];
    const float* att0 = (const float*)d_in[12];
    const float* bo0  = (const float*)d_in[13];
    const float* Wl1  = (const float*)d_in[14];
    const float* bl1  = (const float*)d_in[15];
    const float* Wr1  = (const float*)d_in[16];
    const float* br1  = (const float*)d_in[17];
    const float* att1 = (const float*)d_in[18];
    const float* bo1  = (const float*)d_in[19];
    const float* W2   = (const float*)d_in[20];
    const float* b2   = (const float*)d_in[21];
    const float* g2   = (const float*)d_in[22];
    const float* be2  = (const float*)d_in[23];
    const float* m2   = (const float*)d_in[24];
    const float* v2   = (const float*)d_in[25];

    char* ws = (char*)d_ws;
    const int M = BATCH * NNODES;                        // 16384
    const size_t SZ_BF = (size_t)M * HID * sizeof(bf16_t);   // 8 MB

    int*    noff = (int*)ws;                ws += 2048;
    int*    csrc = (int*)ws;                ws += 32768;
    bf16_t* Wl0t = (bf16_t*)ws;             ws += 256 * 256 * 2;
    bf16_t* Wr0t = (bf16_t*)ws;             ws += 256 * 256 * 2;
    bf16_t* Wl1t = (bf16_t*)ws;             ws += 256 * 256 * 2;
    bf16_t* Wr1t = (bf16_t*)ws;             ws += 256 * 256 * 2;
    bf16_t* H    = (bf16_t*)ws;             ws += SZ_BF;   // node_proj out / edge1 out
    bf16_t* H2   = (bf16_t*)ws;             ws += SZ_BF;   // edge0 out
    bf16_t* XL   = (bf16_t*)ws;             ws += SZ_BF;   // lin_l out
    bf16_t* XR   = (bf16_t*)ws;             ws += SZ_BF;   // lin_r out
    float*  P    = (float*)ws;              ws += BATCH * 16 * HID * 4;

    // ONE head launch: CSR (block 0) + weight packs + node_proj, all
    // dependency-free, absorbed by the first-dispatch drain window.
    head_kernel<<<769, 256, 0, stream>>>(x, W1, b1, g1, be1, m1, v1, H,
                                         ei, Wl0, Wr0, Wl1, Wr1,
                                         noff, csrc, Wl0t, Wr0t, Wl1t, Wr1t);

    // layer 0: XL = H@Wl0+bl0, XR = H@Wr0+br0 (both bf16)
    gemm_kernel<8><<<dim3(2, 512), 256, 0, stream>>>(
        H, Wl0t, Wr0t, XL, XR, bl0, br0);
    edge_kernel<<<NNODES * 8, 256, 0, stream>>>(XL, XR, att0, bo0, noff, csrc, H2);

    // layer 1
    gemm_kernel<8><<<dim3(2, 512), 256, 0, stream>>>(
        H2, Wl1t, Wr1t, XL, XR, bl1, br1);
    edge_kernel<<<NNODES * 8, 256, 0, stream>>>(XL, XR, att1, bo1, noff, csrc, H);

    pool_kernel<<<dim3(BATCH, 16), 256, 0, stream>>>(H, P);
    final_kernel<<<BATCH, 256, 0, stream>>>(P, W2, b2, g2, be2, m2, v2,
                                            (float*)d_out);
}

// Round 19
// 258.142 us; speedup vs baseline: 1.0269x; 1.0269x over previous
//
#include <hip/hip_runtime.h>
#include <hip/hip_bf16.h>
#include <math.h>

// Problem constants (from reference)
#define BATCH   64
#define NNODES  256
#define HID     256
#define HEADS   4
#define CDIM    64
#define NEDGES  8192
#define NEG_SLOPE 0.2f
#define EPS_BN 1e-5f

// All intermediate activations use NODE-MAJOR layout: row = node*64 + batch.
// Lin weights pre-packed into K-tile panels: [K/32][256 n][32 k] bf16.

typedef __bf16 bf16_t;
typedef __bf16 bf16x8 __attribute__((ext_vector_type(8)));
typedef float  f32x4  __attribute__((ext_vector_type(4)));
typedef float  f32x2  __attribute__((ext_vector_type(2)));
typedef unsigned int u32;
typedef u32 u32x4v __attribute__((ext_vector_type(4)));

__device__ __forceinline__ float gelu_f(float x) {
    return 0.5f * x * (1.0f + erff(x * 0.70710678118654752440f));
}

__device__ __forceinline__ f32x2 vmax2(f32x2 a, f32x2 b) {
#if __has_builtin(__builtin_elementwise_max)
    return __builtin_elementwise_max(a, b);
#else
    f32x2 r; r[0] = fmaxf(a[0], b[0]); r[1] = fmaxf(a[1], b[1]); return r;
#endif
}

// bf16 pair (packed in u32) -> 2 floats: 1 VALU per element.
__device__ __forceinline__ f32x2 unpk(u32 u) {
    f32x2 f;
    f[0] = __builtin_bit_cast(float, u << 16);
    f[1] = __builtin_bit_cast(float, u & 0xffff0000u);
    return f;
}

// LDS bank swizzle for 16B chunks.
#define SWZ(r, c) ((c) ^ ((r) & 3) ^ (((r) >> 2) & 3) ^ (((r) >> 4) & 3))

// ---------------------------------------------------------------------------
// HEAD kernel (measured best): CSR at block 0 (latency hidden), packs 1..256,
// node_proj 257..768, single-barrier dbuf K-loop. All dependency-free work
// absorbed by the ~42 us first-dispatch drain window; bandwidth-floor-bound.
// ---------------------------------------------------------------------------
__global__ __launch_bounds__(256, 4) void head_kernel(
        const float* __restrict__ x, const float* __restrict__ W1,
        const float* __restrict__ b1, const float* __restrict__ g1,
        const float* __restrict__ be1, const float* __restrict__ m1,
        const float* __restrict__ v1, bf16_t* __restrict__ H,
        const int* __restrict__ ei,
        const float* __restrict__ Wa, const float* __restrict__ Wb,
        const float* __restrict__ Wc, const float* __restrict__ Wd,
        int* __restrict__ noff, int* __restrict__ csrc,
        bf16_t* __restrict__ Ta, bf16_t* __restrict__ Tb,
        bf16_t* __restrict__ Tc, bf16_t* __restrict__ Td) {
    __shared__ char smem[36 * 1024];
    const int bx  = blockIdx.x;
    const int tid = threadIdx.x;

    if (bx == 0) {
        // ---- CSR build ----
        int* cnt = (int*)smem;
        int* sc  = cnt + NNODES;
        cnt[tid] = 0;
        __syncthreads();
        for (int e = tid; e < NEDGES; e += 256) atomicAdd(&cnt[ei[NEDGES + e]], 1);
        __syncthreads();
        sc[tid] = cnt[tid];
        __syncthreads();
        #pragma unroll
        for (int ofs = 1; ofs < 256; ofs <<= 1) {
            const int t = (tid >= ofs) ? sc[tid - ofs] : 0;
            __syncthreads();
            sc[tid] += t;
            __syncthreads();
        }
        const int excl = sc[tid] - cnt[tid];
        noff[tid] = excl;
        if (tid == 255) noff[NNODES] = sc[255];
        cnt[tid] = excl;
        __syncthreads();
        for (int e = tid; e < NEDGES; e += 256) {
            int d = ei[NEDGES + e];
            int p = atomicAdd(&cnt[d], 1);
            csrc[p] = ei[e];
        }
        return;
    }
    if (bx <= 256) {
        // ---- lin-weight panel pack ----
        float (*tile)[33] = (float(*)[33])smem;
        const int idx = bx - 1, mid = idx >> 6, t = idx & 63;
        const float* in; bf16_t* out;
        if (mid == 0) { in = Wa; out = Ta; }
        else if (mid == 1) { in = Wb; out = Tb; }
        else if (mid == 2) { in = Wc; out = Tc; }
        else { in = Wd; out = Td; }
        const int kt = t >> 3, nt = t & 7;
        const int k0 = kt * 32, n0 = nt * 32;
        const int xx = tid & 31, y = tid >> 5;
        #pragma unroll
        for (int j = 0; j < 4; ++j)
            tile[y + j * 8][xx] = in[(size_t)(k0 + y + j * 8) * 256 + n0 + xx];
        __syncthreads();
        #pragma unroll
        for (int j = 0; j < 4; ++j) {
            const int n = n0 + y + j * 8;
            out[((size_t)kt * 256 + n) * 32 + xx] = (bf16_t)tile[xx][y + j * 8];
        }
        return;
    }

    // ---- node_proj GEMM: H = gelu(BN(x @ W1 + b1)), bf16 node-major out ----
    bf16_t (*As)[32 * 32]  = (bf16_t(*)[32 * 32])smem;
    bf16_t (*Bs)[256 * 32] = (bf16_t(*)[256 * 32])(smem + 4096);
    const int K = 768;
    const int lane = tid & 63;
    const int wv   = tid >> 6;
    const int mblk = (bx - 257) * 32;

    f32x4 acc[2][4];
    #pragma unroll
    for (int f = 0; f < 2; ++f)
        #pragma unroll
        for (int t = 0; t < 4; ++t) acc[f][t] = (f32x4){0.f, 0.f, 0.f, 0.f};

    const int arow = (tid & 127) >> 2;
    const int achk = tid & 3;
    const int gr   = mblk + arow;
    const int arr  = (gr & 63) * 256 + (gr >> 6);    // batch-major source row
    const int fm   = lane & 15, q = lane >> 4;
    const int nq   = tid & 63;
    const int kg   = tid >> 6;

    f32x4 a0, a1;
    f32x4 bw[8];
    if (tid < 128) {
        const float* ap = x + (size_t)arr * K + achk * 8;
        a0 = *(const f32x4*)ap; a1 = *(const f32x4*)(ap + 4);
    }
    {
        const float* wp = W1 + (size_t)(kg * 8) * 256 + nq * 4;
        #pragma unroll
        for (int j = 0; j < 8; ++j) bw[j] = *(const f32x4*)(wp + j * 256);
    }

    #pragma unroll
    for (int kt = 0; kt < 24; ++kt) {
        const int buf = kt & 1;
        if (tid < 128) {
            bf16x8 v;
            #pragma unroll
            for (int j = 0; j < 4; ++j) { v[j] = (bf16_t)a0[j]; v[4 + j] = (bf16_t)a1[j]; }
            *(bf16x8*)(&As[buf][(arow * 4 + SWZ(arow, achk)) * 8]) = v;
        }
        #pragma unroll
        for (int i = 0; i < 4; ++i) {
            const int n = nq * 4 + i;
            bf16x8 v;
            #pragma unroll
            for (int j = 0; j < 8; ++j) v[j] = (bf16_t)bw[j][i];
            *(bf16x8*)(&Bs[buf][(n * 4 + SWZ(n, kg)) * 8]) = v;
        }
        __syncthreads();
        if (kt + 1 < 24) {
            const int k0 = (kt + 1) * 32;
            if (tid < 128) {
                const float* ap = x + (size_t)arr * K + k0 + achk * 8;
                a0 = *(const f32x4*)ap; a1 = *(const f32x4*)(ap + 4);
            }
            const float* wp = W1 + (size_t)(k0 + kg * 8) * 256 + nq * 4;
            #pragma unroll
            for (int j = 0; j < 8; ++j) bw[j] = *(const f32x4*)(wp + j * 256);
        }
        bf16x8 af[2], bfv[4];
        #pragma unroll
        for (int f = 0; f < 2; ++f) {
            const int r = f * 16 + fm;
            af[f] = *(const bf16x8*)(&As[buf][(r * 4 + SWZ(r, q)) * 8]);
        }
        #pragma unroll
        for (int t = 0; t < 4; ++t) {
            const int n = wv * 64 + t * 16 + fm;
            bfv[t] = *(const bf16x8*)(&Bs[buf][(n * 4 + SWZ(n, q)) * 8]);
        }
        #pragma unroll
        for (int f = 0; f < 2; ++f)
            #pragma unroll
            for (int t = 0; t < 4; ++t)
                acc[f][t] = __builtin_amdgcn_mfma_f32_16x16x32_bf16(
                    af[f], bfv[t], acc[f][t], 0, 0, 0);
    }

    const int quad = lane >> 4, cn = lane & 15;
    #pragma unroll
    for (int t = 0; t < 4; ++t) {
        const int n = wv * 64 + t * 16 + cn;
        const float s = g1[n] * rsqrtf(v1[n] + EPS_BN);
        const float shift = (b1[n] - m1[n]) * s + be1[n];
        #pragma unroll
        for (int f = 0; f < 2; ++f) {
            #pragma unroll
            for (int r = 0; r < 4; ++r) {
                const int m = mblk + f * 16 + quad * 4 + r;
                H[(size_t)m * 256 + n] = (bf16_t)gelu_f(acc[f][t][r] * s + shift);
            }
        }
    }
}

// ---------------------------------------------------------------------------
// MFMA bf16 dual GEMM (measured best): tile 32(M) x 256(N), BK=32,
// single-barrier pipelined dbuf, 1024 blocks (4/CU).
// ---------------------------------------------------------------------------
template<int KTILES>
__global__ __launch_bounds__(256, 4) void gemm_kernel(
        const bf16_t* __restrict__ Ap,
        const bf16_t* __restrict__ Bt0, const bf16_t* __restrict__ Bt1,
        bf16_t* __restrict__ C0p, bf16_t* __restrict__ C1p,
        const float* __restrict__ bias0, const float* __restrict__ bias1) {
    __shared__ bf16_t As[2][32 * 32];
    __shared__ bf16_t Bs[2][256 * 32];
    const int K = KTILES * 32;
    const int tid  = threadIdx.x;
    const int lane = tid & 63;
    const int wv   = tid >> 6;
    const int mblk = blockIdx.y * 32;
    const bool second = (blockIdx.x == 1);
    const bf16_t* Bt = second ? Bt1 : Bt0;
    bf16_t* Cp = second ? C1p : C0p;
    const float* bias = second ? bias1 : bias0;

    f32x4 acc[2][4];
    #pragma unroll
    for (int f = 0; f < 2; ++f)
        #pragma unroll
        for (int t = 0; t < 4; ++t) acc[f][t] = (f32x4){0.f, 0.f, 0.f, 0.f};

    const int arow = (tid & 127) >> 2;
    const int achk = tid & 3;
    const int fm   = lane & 15, q = lane >> 4;
    const int bn   = tid >> 2;

    bf16x8 aReg; bf16x8 bReg[4];
    if (tid < 128)
        aReg = *(const bf16x8*)(Ap + (size_t)(mblk + arow) * K + achk * 8);
    {
        const bf16_t* panel = Bt + (size_t)tid * 8;
        #pragma unroll
        for (int c = 0; c < 4; ++c) bReg[c] = *(const bf16x8*)(panel + c * 2048);
    }

    #pragma unroll
    for (int kt = 0; kt < KTILES; ++kt) {
        const int buf = kt & 1;
        if (tid < 128)
            *(bf16x8*)(&As[buf][(arow * 4 + SWZ(arow, achk)) * 8]) = aReg;
        #pragma unroll
        for (int c = 0; c < 4; ++c) {
            const int n = c * 64 + bn;
            *(bf16x8*)(&Bs[buf][(n * 4 + SWZ(n, achk)) * 8]) = bReg[c];
        }
        __syncthreads();
        if (kt + 1 < KTILES) {
            const int k0 = (kt + 1) * 32;
            if (tid < 128)
                aReg = *(const bf16x8*)(Ap + (size_t)(mblk + arow) * K + k0 + achk * 8);
            const bf16_t* panel = Bt + (size_t)(kt + 1) * (256 * 32) + (size_t)tid * 8;
            #pragma unroll
            for (int c = 0; c < 4; ++c) bReg[c] = *(const bf16x8*)(panel + c * 2048);
        }
        bf16x8 af[2], bfv[4];
        #pragma unroll
        for (int f = 0; f < 2; ++f) {
            const int r = f * 16 + fm;
            af[f] = *(const bf16x8*)(&As[buf][(r * 4 + SWZ(r, q)) * 8]);
        }
        #pragma unroll
        for (int t = 0; t < 4; ++t) {
            const int n = wv * 64 + t * 16 + fm;
            bfv[t] = *(const bf16x8*)(&Bs[buf][(n * 4 + SWZ(n, q)) * 8]);
        }
        #pragma unroll
        for (int f = 0; f < 2; ++f)
            #pragma unroll
            for (int t = 0; t < 4; ++t)
                acc[f][t] = __builtin_amdgcn_mfma_f32_16x16x32_bf16(
                    af[f], bfv[t], acc[f][t], 0, 0, 0);
    }

    const int quad = lane >> 4, cn = lane & 15;
    #pragma unroll
    for (int t = 0; t < 4; ++t) {
        const int n = wv * 64 + t * 16 + cn;
        const float bv = bias[n];
        #pragma unroll
        for (int f = 0; f < 2; ++f) {
            #pragma unroll
            for (int r = 0; r < 4; ++r) {
                const int m = mblk + f * 16 + quad * 4 + r;
                Cp[(size_t)m * 256 + n] = (bf16_t)(acc[f][t][r] + bv);
            }
        }
    }
}

// ---------------------------------------------------------------------------
// GATv2 edge softmax + aggregate — 2-chain packed-math (measured best).
// lrelu(z) = max(z, 0.2z); bf16 unpack via bit ops; float2 packed math.
// No online max (logits bounded). Node-major, XCD-swizzled.
// ---------------------------------------------------------------------------
__global__ __launch_bounds__(256) void edge_kernel(
        const bf16_t* __restrict__ XL, const bf16_t* __restrict__ XR,
        const float* __restrict__ att, const float* __restrict__ bo,
        const int* __restrict__ noff, const int* __restrict__ csrc,
        bf16_t* __restrict__ Hout) {
    const int bid  = blockIdx.x;
    const int i    = bid >> 3;
    const int tid  = threadIdx.x;
    const int w    = tid >> 6;
    const int lane = tid & 63;
    const int bg   = lane >> 3;
    const int cg   = lane & 7;
    const int b    = (bid & 7) * 8 + bg;
    const int cbase = w * CDIM + cg * 8;
    const size_t orow = ((size_t)i * BATCH + b) * HID + cbase;
    const float* bor = bo + cbase;

    const int s0 = noff[i], s1 = noff[i + 1];
    if (s0 == s1) {
        bf16x8 ov;
        #pragma unroll
        for (int q = 0; q < 8; ++q) ov[q] = (bf16_t)gelu_f(bor[q]);
        *(bf16x8*)(Hout + orow) = ov;
        return;
    }

    f32x2 att2[4], xi2[4];
    {
        const u32x4v xr = *(const u32x4v*)(XR + orow);
        #pragma unroll
        for (int k = 0; k < 4; ++k) {
            att2[k] = *(const f32x2*)(att + cbase + 2 * k);
            xi2[k]  = unpk(xr[k]);
        }
    }

    const bf16_t* XLb = XL + (size_t)b * HID + cbase;
    const size_t RSTR = (size_t)BATCH * HID;

    float dA = 0.f, dB = 0.f;
    f32x2 accA[4], accB[4];
    #pragma unroll
    for (int k = 0; k < 4; ++k) {
        accA[k] = (f32x2){0.f, 0.f};
        accB[k] = (f32x2){0.f, 0.f};
    }

    int jA = csrc[s0];
    int jB = csrc[(s0 + 1 < s1) ? s0 + 1 : s0];
    u32x4v uA = *(const u32x4v*)(XLb + (size_t)jA * RSTR);
    u32x4v uB = *(const u32x4v*)(XLb + (size_t)jB * RSTR);

    for (int e = s0; e < s1; e += 2) {
        const int nA = (e + 2 < s1) ? e + 2 : s0;
        const int nB = (e + 3 < s1) ? e + 3 : s0;
        const int jnA = csrc[nA], jnB = csrc[nB];
        const u32x4v unA = *(const u32x4v*)(XLb + (size_t)jnA * RSTR);
        const u32x4v unB = *(const u32x4v*)(XLb + (size_t)jnB * RSTR);

        f32x2 fA[4], fB[4];
        f32x2 pA2 = (f32x2){0.f, 0.f}, pB2 = (f32x2){0.f, 0.f};
        #pragma unroll
        for (int k = 0; k < 4; ++k) {
            fA[k] = unpk(uA[k]);
            fB[k] = unpk(uB[k]);
            const f32x2 zA = xi2[k] + fA[k];
            const f32x2 zB = xi2[k] + fB[k];
            const f32x2 mA = vmax2(zA, zA * 0.2f);
            const f32x2 mB = vmax2(zB, zB * 0.2f);
            pA2 += att2[k] * mA;
            pB2 += att2[k] * mB;
        }
        float pA = pA2[0] + pA2[1];
        float pB = pB2[0] + pB2[1];
        pA += __shfl_xor(pA, 1, 64);  pB += __shfl_xor(pB, 1, 64);
        pA += __shfl_xor(pA, 2, 64);  pB += __shfl_xor(pB, 2, 64);
        pA += __shfl_xor(pA, 4, 64);  pB += __shfl_xor(pB, 4, 64);

        const float wA = __expf(pA);
        const float wB = ((e + 1 < s1) ? 1.f : 0.f) * __expf(pB);
        dA += wA; dB += wB;
        const f32x2 wA2 = (f32x2){wA, wA};
        const f32x2 wB2 = (f32x2){wB, wB};
        #pragma unroll
        for (int k = 0; k < 4; ++k) {
            accA[k] += wA2 * fA[k];
            accB[k] += wB2 * fB[k];
        }
        uA = unA; uB = unB;
    }

    const float inv = 1.0f / (dA + dB + 1e-16f);
    bf16x8 ov;
    #pragma unroll
    for (int k = 0; k < 4; ++k) {
        const f32x2 bo2 = *(const f32x2*)(bor + 2 * k);
        const f32x2 o2 = (accA[k] + accB[k]) * inv + bo2;
        ov[2 * k]     = (bf16_t)gelu_f(o2[0]);
        ov[2 * k + 1] = (bf16_t)gelu_f(o2[1]);
    }
    *(bf16x8*)(Hout + orow) = ov;
}

// ---------------------------------------------------------------------------
// Mean-pool partials: grid (64 b, 16 c); block sums 16 nodes (short chains).
// ---------------------------------------------------------------------------
__global__ __launch_bounds__(256) void pool_kernel(const bf16_t* __restrict__ H1,
                                                   float* __restrict__ P) {
    const int b = blockIdx.x, c = blockIdx.y, f = threadIdx.x;
    const bf16_t* p = H1 + ((size_t)(c * 16) * BATCH + b) * HID + f;
    float s = 0.f;
    #pragma unroll
    for (int n = 0; n < 16; ++n) s += (float)p[(size_t)n * BATCH * HID];
    P[((size_t)b * 16 + c) * HID + f] = s;
}

// ---------------------------------------------------------------------------
// Output proj: out = gelu(BN(pooled @ W2 + b2)), pooled from 16 partials.
// ---------------------------------------------------------------------------
__global__ __launch_bounds__(256) void final_kernel(
        const float* __restrict__ P, const float* __restrict__ W2,
        const float* __restrict__ b2, const float* __restrict__ g2,
        const float* __restrict__ be2, const float* __restrict__ m2,
        const float* __restrict__ v2, float* __restrict__ out) {
    __shared__ float pl[HID];
    const int b = blockIdx.x, f = threadIdx.x;
    float s4 = 0.f;
    #pragma unroll
    for (int c = 0; c < 16; ++c) s4 += P[((size_t)b * 16 + c) * HID + f];
    pl[f] = s4 * (1.0f / (float)NNODES);
    __syncthreads();
    float s = 0.f;
    for (int k = 0; k < HID; ++k) s += pl[k] * W2[(size_t)k * HID + f];
    s += b2[f];
    const float scale = g2[f] * rsqrtf(v2[f] + EPS_BN);
    s = (s - m2[f]) * scale + be2[f];
    out[b * HID + f] = gelu_f(s);
}

// ---------------------------------------------------------------------------
extern "C" void kernel_launch(void* const* d_in, const int* in_sizes, int n_in,
                              void* d_out, int out_size, void* d_ws, size_t ws_size,
                              hipStream_t stream) {
    const float* x    = (const float*)d_in[0];
    const int*   ei   = (const int*)d_in[1];
    const float* W1   = (const float*)d_in[2];
    const float* b1   = (const float*)d_in[3];
    const float* g1   = (const float*)d_in[4];
    const float* be1  = (const float*)d_in[5];
    const float* m1   = (const float*)d_in[6];
    const float* v1   = (const float*)d_in[7];
    const float* Wl0  = (const float*)d_in[8];
    const float* bl0  = (const float*)d_in[9];
    const float* Wr0  = (const float*)d_in[10];
    const float* br0  = (const float*)d_in[11];
    const float* att0 = (const float*)d_in[12];
    const float* bo0  = (const float*)d_in[13];
    const float* Wl1  = (const float*)d_in[14];
    const float* bl1  = (const float*)d_in[15];
    const float* Wr1  = (const float*)d_in[16];
    const float* br1  = (const float*)d_in[17];
    const float* att1 = (const float*)d_in[18];
    const float* bo1  = (const float*)d_in[19];
    const float* W2   = (const float*)d_in[20];
    const float* b2   = (const float*)d_in[21];
    const float* g2   = (const float*)d_in[22];
    const float* be2  = (const float*)d_in[23];
    const float* m2   = (const float*)d_in[24];
    const float* v2   = (const float*)d_in[25];

    char* ws = (char*)d_ws;
    const int M = BATCH * NNODES;                        // 16384
    const size_t SZ_BF = (size_t)M * HID * sizeof(bf16_t);   // 8 MB

    int*    noff = (int*)ws;                ws += 2048;
    int*    csrc = (int*)ws;                ws += 32768;
    bf16_t* Wl0t = (bf16_t*)ws;             ws += 256 * 256 * 2;
    bf16_t* Wr0t = (bf16_t*)ws;             ws += 256 * 256 * 2;
    bf16_t* Wl1t = (bf16_t*)ws;             ws += 256 * 256 * 2;
    bf16_t* Wr1t = (bf16_t*)ws;             ws += 256 * 256 * 2;
    bf16_t* H    = (bf16_t*)ws;             ws += SZ_BF;   // node_proj out / edge1 out
    bf16_t* H2   = (bf16_t*)ws;             ws += SZ_BF;   // edge0 out
    bf16_t* XL   = (bf16_t*)ws;             ws += SZ_BF;   // lin_l out
    bf16_t* XR   = (bf16_t*)ws;             ws += SZ_BF;   // lin_r out
    float*  P    = (float*)ws;              ws += BATCH * 16 * HID * 4;

    // ONE head launch: CSR (block 0) + weight packs + node_proj, all
    // dependency-free, absorbed by the first-dispatch drain window.
    head_kernel<<<769, 256, 0, stream>>>(x, W1, b1, g1, be1, m1, v1, H,
                                         ei, Wl0, Wr0, Wl1, Wr1,
                                         noff, csrc, Wl0t, Wr0t, Wl1t, Wr1t);

    // layer 0: XL = H@Wl0+bl0, XR = H@Wr0+br0 (both bf16)
    gemm_kernel<8><<<dim3(2, 512), 256, 0, stream>>>(
        H, Wl0t, Wr0t, XL, XR, bl0, br0);
    edge_kernel<<<NNODES * 8, 256, 0, stream>>>(XL, XR, att0, bo0, noff, csrc, H2);

    // layer 1
    gemm_kernel<8><<<dim3(2, 512), 256, 0, stream>>>(
        H2, Wl1t, Wr1t, XL, XR, bl1, br1);
    edge_kernel<<<NNODES * 8, 256, 0, stream>>>(XL, XR, att1, bo1, noff, csrc, H);

    pool_kernel<<<dim3(BATCH, 16), 256, 0, stream>>>(H, P);
    final_kernel<<<BATCH, 256, 0, stream>>>(P, W2, b2, g2, be2, m2, v2,
                                            (float*)d_out);
}